// Round 1
// baseline (4709.980 us; speedup 1.0000x reference)
//
#include <hip/hip_runtime.h>
#include <math.h>

typedef short s16;
typedef __attribute__((ext_vector_type(8))) short short8;
typedef __attribute__((ext_vector_type(4))) float f32x4;

#define NTOK 49
#define CDIM 192
#define NH   6
#define HDIM 32
#define FFD  768
#define QSCALE 0.17677669529663687f

__device__ __forceinline__ s16 f2bf(float f) {
    union { float f; unsigned u; } v; v.f = f;
    unsigned r = v.u + 0x7fffu + ((v.u >> 16) & 1u);
    return (s16)(r >> 16);
}

// ---- prep: cast all weights fp32 -> bf16 bits into ws ----
// segments (elements): qkv 221184 | proj 73728 | ffn_w1 294912 | ffn_w2 294912
__global__ void prep_weights(const float* __restrict__ qkv_w,
                             const float* __restrict__ proj_w,
                             const float* __restrict__ w1,
                             const float* __restrict__ w2,
                             s16* __restrict__ wb) {
    int idx = blockIdx.x * 256 + threadIdx.x;
    if (idx < 221184)       wb[idx] = f2bf(qkv_w[idx]);
    else if (idx < 294912)  wb[idx] = f2bf(proj_w[idx - 221184]);
    else if (idx < 589824)  wb[idx] = f2bf(w1[idx - 294912]);
    else if (idx < 884736)  wb[idx] = f2bf(w2[idx - 589824]);
}

// ---- prep: expand rel_bias -> bias_pad[d][h][q<49][k<64] f32, k>=49 = -1e9 (mask) ----
__global__ void prep_bias(const float* __restrict__ rel_bias, float* __restrict__ bias_pad) {
    int idx = blockIdx.x * 256 + threadIdx.x;
    if (idx >= 2 * NH * NTOK * 64) return;
    int k = idx & 63;
    int q = (idx >> 6) % NTOK;
    int h = ((idx >> 6) / NTOK) % NH;
    int d = idx / (64 * NTOK * NH);
    float v;
    if (k < NTOK) {
        int qi = q / 7, qj = q % 7, ki = k / 7, kj = k % 7;
        int r = (qi - ki + 6) * 13 + (qj - kj + 6);
        v = rel_bias[(d * 169 + r) * NH + h];
    } else {
        v = -1e9f;
    }
    bias_pad[idx] = v;
}

// Fused Swin block-pair. 1 workgroup = 1 window (49 tokens padded to 64 rows).
// 256 threads = 4 waves; wave w owns M-tile w for attention, a c-tile range for GEMMs.
// MFMA layouts (gfx950, HW-verified):
//   A frag: row = lane&15, k = 8*(lane>>4)+j (16B contiguous)
//   B frag: col = lane&15, k = 8*(lane>>4)+j (16B contiguous)
//   D frag: col = lane&15, row = 4*(lane>>4)+reg
__global__ __launch_bounds__(256, 1)
void swin_fused(const float* __restrict__ x_in,
                const float* __restrict__ n1w, const float* __restrict__ n1b,
                const s16*  __restrict__ qkv_wb, const float* __restrict__ qkv_b,
                const float* __restrict__ bias_pad,
                const s16*  __restrict__ proj_wb, const float* __restrict__ proj_b,
                const float* __restrict__ n2w, const float* __restrict__ n2b,
                const s16*  __restrict__ w1b, const float* __restrict__ fb1,
                const s16*  __restrict__ w2b, const float* __restrict__ fb2,
                float* __restrict__ out)
{
    // LDS: 38,416 + 25,600 + 77,824 + 9,216 = 151,056 B  (< 160 KiB)
    __shared__ float xb[NTOK][196];                 // fp32 trunk (residual)
    __shared__ s16   hb[64][200];                   // post-LN h / attn output o (bf16 bits); rows 49..63 stay 0
    __shared__ __align__(16) char ubuf[77824];      // union: {q|k [64][392] + vT [192][72]}  OR  {FFN t [64][392]}
    __shared__ s16   sb[64][72];                    // softmax probs (bf16, unnormalized)
    s16 (*qk)[392] = (s16(*)[392])ubuf;             // cols 0..191 = q (pre-scaled), 192..383 = k
    s16 *vt        = (s16*)(ubuf + 50176);          // [h*32+d][n] transposed V
    s16 (*tb)[392] = (s16(*)[392])ubuf;             // FFN hidden chunk (384 cols)

    const int tid  = threadIdx.x;
    const int wv   = tid >> 6;
    const int lane = tid & 63;
    const int lr   = lane & 15;
    const int lg   = lane >> 4;
    const int win  = blockIdx.x;

    // ---- stage x into LDS; zero hb pad rows ----
    {
        const float4* xg = (const float4*)(x_in + (size_t)win * (NTOK * CDIM));
        for (int idx = tid; idx < NTOK * CDIM / 4; idx += 256) {
            float4 v = xg[idx];
            int n = (idx * 4) / CDIM, c = (idx * 4) % CDIM;
            xb[n][c] = v.x; xb[n][c + 1] = v.y; xb[n][c + 2] = v.z; xb[n][c + 3] = v.w;
        }
        for (int idx = tid; idx < 15 * 200; idx += 256)
            hb[NTOK + idx / 200][idx % 200] = 0;
    }
    __syncthreads();

    for (int blk = 0; blk < 2; ++blk) {
        const s16* qw  = qkv_wb + (size_t)blk * (3 * CDIM * CDIM);
        const s16* pw  = proj_wb + (size_t)blk * (CDIM * CDIM);
        const s16* f1w = w1b + (size_t)blk * (FFD * CDIM);
        const s16* f2w = w2b + (size_t)blk * (CDIM * FFD);

        // ================= LN1 : xb -> hb (bf16) =================
        if (tid < 196) {
            int r = tid >> 2, q4 = tid & 3;
            float s = 0.f, s2 = 0.f;
            for (int c = q4; c < CDIM; c += 4) { float v = xb[r][c]; s += v; s2 += v * v; }
            s  += __shfl_xor(s, 1);  s  += __shfl_xor(s, 2);
            s2 += __shfl_xor(s2, 1); s2 += __shfl_xor(s2, 2);
            float mu = s * (1.f / CDIM);
            float rs = rsqrtf(s2 * (1.f / CDIM) - mu * mu + 1e-5f);
            for (int c = q4; c < CDIM; c += 4)
                hb[r][c] = f2bf((xb[r][c] - mu) * rs * n1w[blk * CDIM + c] + n1b[blk * CDIM + c]);
        }
        __syncthreads();

        // ================= QKV GEMM: hb[64,192] @ qkv_w^T -> q,k (qk) and vT =================
        {
            short8 Af[4][6];
            #pragma unroll
            for (int m = 0; m < 4; ++m)
                #pragma unroll
                for (int k = 0; k < 6; ++k)
                    Af[m][k] = *(const short8*)&hb[m * 16 + lr][k * 32 + lg * 8];

            const int ct0 = wv * 9, ct1 = ct0 + 9;
            short8 Bf[6], Bn[6];
            {
                const s16* p = qw + (size_t)(ct0 * 16 + lr) * CDIM + lg * 8;
                #pragma unroll
                for (int k = 0; k < 6; ++k) Bf[k] = *(const short8*)(p + k * 32);
            }
            for (int ct = ct0; ct < ct1; ++ct) {
                if (ct + 1 < ct1) {
                    const s16* p = qw + (size_t)((ct + 1) * 16 + lr) * CDIM + lg * 8;
                    #pragma unroll
                    for (int k = 0; k < 6; ++k) Bn[k] = *(const short8*)(p + k * 32);
                }
                f32x4 acc[4];
                #pragma unroll
                for (int m = 0; m < 4; ++m) { f32x4 z = {0.f, 0.f, 0.f, 0.f}; acc[m] = z; }
                #pragma unroll
                for (int k = 0; k < 6; ++k)
                    #pragma unroll
                    for (int m = 0; m < 4; ++m)
                        acc[m] = __builtin_amdgcn_mfma_f32_16x16x32_bf16(Af[m][k], Bf[k], acc[m], 0, 0, 0);
                const int c = ct * 16 + lr;
                const float bias = qkv_b[blk * 3 * CDIM + c];
                #pragma unroll
                for (int m = 0; m < 4; ++m)
                    #pragma unroll
                    for (int j = 0; j < 4; ++j) {
                        int row = m * 16 + lg * 4 + j;
                        float v = acc[m][j] + bias;
                        if (c < 384) {                       // uniform per tile (16 | 384)
                            if (c < 192) v *= QSCALE;        // pre-scale q
                            qk[row][c] = f2bf(v);
                        } else {
                            vt[(c - 384) * 72 + row] = f2bf(v);   // transposed V
                        }
                    }
                if (ct + 1 < ct1) {
                    #pragma unroll
                    for (int k = 0; k < 6; ++k) Bf[k] = Bn[k];
                }
            }
        }
        __syncthreads();

        // ================= Attention: wave wv owns q-rows [wv*16, wv*16+16) =================
        {
            const int m = wv;
            for (int h = 0; h < NH; ++h) {
                short8 Aq = *(const short8*)&qk[m * 16 + lr][h * HDIM + lg * 8];
                f32x4 sc[4];
                #pragma unroll
                for (int ct = 0; ct < 4; ++ct) {
                    short8 Bk = *(const short8*)&qk[ct * 16 + lr][CDIM + h * HDIM + lg * 8];
                    f32x4 z = {0.f, 0.f, 0.f, 0.f};
                    sc[ct] = __builtin_amdgcn_mfma_f32_16x16x32_bf16(Aq, Bk, z, 0, 0, 0);
                }
                const float* bp = bias_pad + (size_t)(blk * NH + h) * NTOK * 64;
                float inv[4];
                #pragma unroll
                for (int j = 0; j < 4; ++j) {
                    int q = m * 16 + lg * 4 + j;
                    float v0 = sc[0][j], v1 = sc[1][j], v2 = sc[2][j], v3 = sc[3][j];
                    if (q < NTOK) {
                        const float* bq = bp + q * 64 + lr;
                        v0 += bq[0]; v1 += bq[16]; v2 += bq[32]; v3 += bq[48];
                    }
                    float mx = fmaxf(fmaxf(v0, v1), fmaxf(v2, v3));
                    #pragma unroll
                    for (int msk = 1; msk < 16; msk <<= 1) mx = fmaxf(mx, __shfl_xor(mx, msk));
                    v0 = __expf(v0 - mx); v1 = __expf(v1 - mx);
                    v2 = __expf(v2 - mx); v3 = __expf(v3 - mx);
                    float sum = v0 + v1 + v2 + v3;
                    #pragma unroll
                    for (int msk = 1; msk < 16; msk <<= 1) sum += __shfl_xor(sum, msk);
                    inv[j] = 1.f / sum;                      // normalize at PV epilogue
                    int row = m * 16 + lg * 4 + j;
                    sb[row][lr]      = f2bf(v0);
                    sb[row][16 + lr] = f2bf(v1);
                    sb[row][32 + lr] = f2bf(v2);
                    sb[row][48 + lr] = f2bf(v3);
                }
                // PV: o = P @ V   (A from sb, same wave -> in-order DS pipe, no barrier)
                short8 Ap0 = *(const short8*)&sb[m * 16 + lr][lg * 8];
                short8 Ap1 = *(const short8*)&sb[m * 16 + lr][32 + lg * 8];
                #pragma unroll
                for (int cb = 0; cb < 2; ++cb) {
                    const s16* vrow = vt + (size_t)(h * HDIM + cb * 16 + lr) * 72;
                    short8 Bv0 = *(const short8*)(vrow + lg * 8);
                    short8 Bv1 = *(const short8*)(vrow + 32 + lg * 8);
                    f32x4 z = {0.f, 0.f, 0.f, 0.f};
                    f32x4 o = __builtin_amdgcn_mfma_f32_16x16x32_bf16(Ap0, Bv0, z, 0, 0, 0);
                    o = __builtin_amdgcn_mfma_f32_16x16x32_bf16(Ap1, Bv1, o, 0, 0, 0);
                    #pragma unroll
                    for (int j = 0; j < 4; ++j) {
                        int row = m * 16 + lg * 4 + j;
                        if (row < NTOK) hb[row][h * HDIM + cb * 16 + lr] = f2bf(o[j] * inv[j]);
                    }
                }
            }
        }
        __syncthreads();

        // ================= proj: hb(o) @ proj_w^T + b + xb -> xb =================
        {
            short8 Af[4][6];
            #pragma unroll
            for (int m = 0; m < 4; ++m)
                #pragma unroll
                for (int k = 0; k < 6; ++k)
                    Af[m][k] = *(const short8*)&hb[m * 16 + lr][k * 32 + lg * 8];

            const int ct0 = wv * 3, ct1 = ct0 + 3;
            short8 Bf[6], Bn[6];
            {
                const s16* p = pw + (size_t)(ct0 * 16 + lr) * CDIM + lg * 8;
                #pragma unroll
                for (int k = 0; k < 6; ++k) Bf[k] = *(const short8*)(p + k * 32);
            }
            for (int ct = ct0; ct < ct1; ++ct) {
                if (ct + 1 < ct1) {
                    const s16* p = pw + (size_t)((ct + 1) * 16 + lr) * CDIM + lg * 8;
                    #pragma unroll
                    for (int k = 0; k < 6; ++k) Bn[k] = *(const short8*)(p + k * 32);
                }
                f32x4 acc[4];
                #pragma unroll
                for (int m = 0; m < 4; ++m) { f32x4 z = {0.f, 0.f, 0.f, 0.f}; acc[m] = z; }
                #pragma unroll
                for (int k = 0; k < 6; ++k)
                    #pragma unroll
                    for (int m = 0; m < 4; ++m)
                        acc[m] = __builtin_amdgcn_mfma_f32_16x16x32_bf16(Af[m][k], Bf[k], acc[m], 0, 0, 0);
                const int c = ct * 16 + lr;
                const float bias = proj_b[blk * CDIM + c];
                #pragma unroll
                for (int m = 0; m < 4; ++m)
                    #pragma unroll
                    for (int j = 0; j < 4; ++j) {
                        int row = m * 16 + lg * 4 + j;
                        if (row < NTOK) xb[row][c] = acc[m][j] + bias + xb[row][c];
                    }
                if (ct + 1 < ct1) {
                    #pragma unroll
                    for (int k = 0; k < 6; ++k) Bf[k] = Bn[k];
                }
            }
        }
        __syncthreads();

        // ================= LN2 : xb -> hb =================
        if (tid < 196) {
            int r = tid >> 2, q4 = tid & 3;
            float s = 0.f, s2 = 0.f;
            for (int c = q4; c < CDIM; c += 4) { float v = xb[r][c]; s += v; s2 += v * v; }
            s  += __shfl_xor(s, 1);  s  += __shfl_xor(s, 2);
            s2 += __shfl_xor(s2, 1); s2 += __shfl_xor(s2, 2);
            float mu = s * (1.f / CDIM);
            float rs = rsqrtf(s2 * (1.f / CDIM) - mu * mu + 1e-5f);
            for (int c = q4; c < CDIM; c += 4)
                hb[r][c] = f2bf((xb[r][c] - mu) * rs * n2w[blk * CDIM + c] + n2b[blk * CDIM + c]);
        }
        __syncthreads();

        // ================= FFN (chunked over F: 2 x 384) =================
        {
            f32x4 acc2[3][4];
            #pragma unroll
            for (int cc = 0; cc < 3; ++cc)
                #pragma unroll
                for (int m = 0; m < 4; ++m) { f32x4 z = {0.f, 0.f, 0.f, 0.f}; acc2[cc][m] = z; }

            for (int ch = 0; ch < 2; ++ch) {
                // ---- FFN1 chunk: hb @ w1^T -> gelu -> tb[64][384] ----
                {
                    short8 Af[4][6];
                    #pragma unroll
                    for (int m = 0; m < 4; ++m)
                        #pragma unroll
                        for (int k = 0; k < 6; ++k)
                            Af[m][k] = *(const short8*)&hb[m * 16 + lr][k * 32 + lg * 8];

                    const int ct0 = wv * 6, ct1 = ct0 + 6;
                    short8 Bf[6], Bn[6];
                    {
                        const s16* p = f1w + (size_t)(ch * 384 + ct0 * 16 + lr) * CDIM + lg * 8;
                        #pragma unroll
                        for (int k = 0; k < 6; ++k) Bf[k] = *(const short8*)(p + k * 32);
                    }
                    for (int ct = ct0; ct < ct1; ++ct) {
                        if (ct + 1 < ct1) {
                            const s16* p = f1w + (size_t)(ch * 384 + (ct + 1) * 16 + lr) * CDIM + lg * 8;
                            #pragma unroll
                            for (int k = 0; k < 6; ++k) Bn[k] = *(const short8*)(p + k * 32);
                        }
                        f32x4 acc[4];
                        #pragma unroll
                        for (int m = 0; m < 4; ++m) { f32x4 z = {0.f, 0.f, 0.f, 0.f}; acc[m] = z; }
                        #pragma unroll
                        for (int k = 0; k < 6; ++k)
                            #pragma unroll
                            for (int m = 0; m < 4; ++m)
                                acc[m] = __builtin_amdgcn_mfma_f32_16x16x32_bf16(Af[m][k], Bf[k], acc[m], 0, 0, 0);
                        const int cl = ct * 16 + lr;                 // col within chunk [0,384)
                        const float bias = fb1[blk * FFD + ch * 384 + cl];
                        #pragma unroll
                        for (int m = 0; m < 4; ++m)
                            #pragma unroll
                            for (int j = 0; j < 4; ++j) {
                                int row = m * 16 + lg * 4 + j;
                                float v = acc[m][j] + bias;
                                v = 0.5f * v * (1.f + erff(v * 0.70710678118654752f));  // exact gelu
                                tb[row][cl] = f2bf(v);
                            }
                        if (ct + 1 < ct1) {
                            #pragma unroll
                            for (int k = 0; k < 6; ++k) Bf[k] = Bn[k];
                        }
                    }
                }
                __syncthreads();
                // ---- FFN2 partial: acc2 += tb @ w2_chunk^T ----
                {
                    const int c0t = wv * 3;
                    short8 B2[3], B2n[3], A2[4];
                    #pragma unroll
                    for (int cc = 0; cc < 3; ++cc) {
                        int c = (c0t + cc) * 16 + lr;
                        B2[cc] = *(const short8*)(f2w + (size_t)c * FFD + ch * 384 + lg * 8);
                    }
                    for (int kt = 0; kt < 12; ++kt) {
                        if (kt < 11) {
                            #pragma unroll
                            for (int cc = 0; cc < 3; ++cc) {
                                int c = (c0t + cc) * 16 + lr;
                                B2n[cc] = *(const short8*)(f2w + (size_t)c * FFD + ch * 384 + (kt + 1) * 32 + lg * 8);
                            }
                        }
                        #pragma unroll
                        for (int m = 0; m < 4; ++m)
                            A2[m] = *(const short8*)&tb[m * 16 + lr][kt * 32 + lg * 8];
                        #pragma unroll
                        for (int cc = 0; cc < 3; ++cc)
                            #pragma unroll
                            for (int m = 0; m < 4; ++m)
                                acc2[cc][m] = __builtin_amdgcn_mfma_f32_16x16x32_bf16(A2[m], B2[cc], acc2[cc][m], 0, 0, 0);
                        if (kt < 11) {
                            #pragma unroll
                            for (int cc = 0; cc < 3; ++cc) B2[cc] = B2n[cc];
                        }
                    }
                }
                __syncthreads();   // before next chunk overwrites tb
            }
            // ---- FFN2 epilogue: xb += acc2 + b2 ----
            #pragma unroll
            for (int cc = 0; cc < 3; ++cc) {
                const int c = (wv * 3 + cc) * 16 + lr;
                const float bias = fb2[blk * CDIM + c];
                #pragma unroll
                for (int m = 0; m < 4; ++m)
                    #pragma unroll
                    for (int j = 0; j < 4; ++j) {
                        int row = m * 16 + lg * 4 + j;
                        if (row < NTOK) xb[row][c] = acc2[cc][m][j] + bias + xb[row][c];
                    }
            }
        }
        __syncthreads();
    }

    // ---- write out ----
    {
        float* ow = out + (size_t)win * (NTOK * CDIM);
        for (int idx = tid; idx < NTOK * CDIM / 4; idx += 256) {
            int n = (idx * 4) / CDIM, c = (idx * 4) % CDIM;
            float4 v = make_float4(xb[n][c], xb[n][c + 1], xb[n][c + 2], xb[n][c + 3]);
            ((float4*)ow)[idx] = v;
        }
    }
}

extern "C" void kernel_launch(void* const* d_in, const int* in_sizes, int n_in,
                              void* d_out, int out_size, void* d_ws, size_t ws_size,
                              hipStream_t stream) {
    const float* x      = (const float*)d_in[0];
    // d_in[1] = window_indices (unused: heightmerging is None)
    const float* n1w    = (const float*)d_in[2];
    const float* n1b    = (const float*)d_in[3];
    const float* qkv_w  = (const float*)d_in[4];
    const float* qkv_b  = (const float*)d_in[5];
    const float* rel    = (const float*)d_in[6];
    const float* proj_w = (const float*)d_in[7];
    const float* proj_b = (const float*)d_in[8];
    const float* n2w    = (const float*)d_in[9];
    const float* n2b    = (const float*)d_in[10];
    const float* w1     = (const float*)d_in[11];
    const float* b1     = (const float*)d_in[12];
    const float* w2     = (const float*)d_in[13];
    const float* b2     = (const float*)d_in[14];

    s16*   wb   = (s16*)d_ws;                            // 884736 bf16 (1.77 MB)
    float* bpad = (float*)((char*)d_ws + 884736 * 2);    // 2*6*49*64 f32 (150 KB)

    prep_weights<<<3456, 256, 0, stream>>>(qkv_w, proj_w, w1, w2, wb);
    prep_bias<<<147, 256, 0, stream>>>(rel, bpad);

    const s16* qkv_wb  = wb;
    const s16* proj_wb = wb + 221184;
    const s16* w1b     = wb + 294912;
    const s16* w2b     = wb + 589824;

    swin_fused<<<8192, 256, 0, stream>>>(x, n1w, n1b, qkv_wb, qkv_b, bpad,
                                         proj_wb, proj_b, n2w, n2b,
                                         w1b, b1, w2b, b2, (float*)d_out);
}